// Round 3
// baseline (20643.858 us; speedup 1.0000x reference)
//
#include <hip/hip_runtime.h>
#include <hip/hip_bf16.h>
#include <math.h>

#define IDIM 128
#define HDIM 512
#define SDIM 64
#define BATCH 128
#define MAXT 259
#define G4 2048
#define KTOT 704   // 128 (x) + 64 (rt) + 512 (h)
#define ROUT 194   // 64 + 128 + 2

typedef __hip_bfloat16 bf16;

__device__ __forceinline__ float sigmoidf_(float v) { return 1.f / (1.f + expf(-v)); }
__device__ __forceinline__ float b2f(bf16 v) { return __bfloat162float(v); }
__device__ __forceinline__ float load_in(const void* p, size_t i, int isf32) {
    return isf32 ? ((const float*)p)[i] : b2f(((const bf16*)p)[i]);
}

// Detect input dtype from first 256 uint16s of Wih (see analysis): f32 data has
// random low-halves -> some bf16-exponent >= 0x8F; true bf16 weights never do.
__global__ void detect_kernel(const unsigned short* __restrict__ w, int* __restrict__ flag) {
    if (threadIdx.x == 0) {
        int isf32 = 0;
        for (int i = 0; i < 256; i++) {
            int e = (w[i] >> 7) & 0xFF;
            if (e >= 0x8F) isf32 = 1;
        }
        *flag = isf32;
    }
}

// Combined gate-interleaved f32 weights: row j'=4u+gate <- row gate*512+u of [Wih|Whh].
__global__ void prep_kernel(const void* __restrict__ Wih, const void* __restrict__ bih,
                            const void* __restrict__ Whh, const void* __restrict__ bhh,
                            float* __restrict__ Wc, float* __restrict__ bc,
                            const int* __restrict__ flag) {
    int isf32 = *flag;
    int jp = blockIdx.x;
    int u = jp >> 2, gate = jp & 3;
    int src = gate * HDIM + u;
    float* dst = Wc + (size_t)jp * KTOT;
    for (int k = threadIdx.x; k < KTOT; k += blockDim.x)
        dst[k] = (k < 192) ? load_in(Wih, (size_t)src * 192 + k, isf32)
                           : load_in(Whh, (size_t)src * HDIM + (k - 192), isf32);
    if (threadIdx.x == 0)
        bc[jp] = load_in(bih, src, isf32) + load_in(bhh, src, isf32);
}

__global__ void wr_conv_kernel(const void* __restrict__ Wr, const void* __restrict__ br,
                               float* __restrict__ Wrf, float* __restrict__ brf,
                               const int* __restrict__ flag) {
    int isf32 = *flag;
    int j = blockIdx.x;
    for (int k = threadIdx.x; k < HDIM; k += blockDim.x)
        Wrf[(size_t)j * HDIM + k] = load_in(Wr, (size_t)j * HDIM + k, isf32);
    if (threadIdx.x == 0) brf[j] = load_in(br, j, isf32);
}

// Gates GEMM (128x2048, K=704) + fused LSTM cell. 32x32 tile, 2x2/thread, 256 blocks.
__global__ __launch_bounds__(256) void gates_kernel(
        const void* __restrict__ x, size_t xoff,   // element offset of x[t]
        const float* __restrict__ Wc, const float* __restrict__ bc,
        const float* __restrict__ hprev, const float* __restrict__ rt,
        float* __restrict__ hnext, float* __restrict__ c,
        const int* __restrict__ flag, int k0) {
    __shared__ float xs[32][68];
    __shared__ float wsh[32][68];
    int isf32 = *flag;
    int bx = blockIdx.x;
    int bm = bx & 3, bn = bx >> 2;
    int b0 = bm * 32, j0 = bn * 32;
    int tid = threadIdx.x;
    int ty = tid >> 4, tx = tid & 15;
    int r0 = 2 * ty, r1 = r0 + 1, c0 = 2 * tx, c1 = c0 + 1;
    float acc00 = 0.f, acc01 = 0.f, acc10 = 0.f, acc11 = 0.f;

    for (int kc = k0; kc < KTOT; kc += 64) {
        #pragma unroll
        for (int i = 0; i < 8; i++) {
            int idx = tid + i * 256;
            int r = idx >> 6, kk = idx & 63;
            int k = kc + kk;
            int b = b0 + r;
            float v;
            if (k < 192) {
                v = (k < 128) ? load_in(x, xoff + (size_t)b * IDIM + k, isf32)
                              : rt[b * SDIM + (k - 128)];
            } else {
                v = hprev[b * HDIM + (k - 192)];
            }
            xs[r][kk] = v;
            wsh[r][kk] = Wc[(size_t)(j0 + r) * KTOT + k];
        }
        __syncthreads();
        #pragma unroll
        for (int kk = 0; kk < 64; kk++) {
            float a0 = xs[r0][kk], a1 = xs[r1][kk];
            float w0 = wsh[c0][kk], w1 = wsh[c1][kk];
            acc00 += a0 * w0; acc01 += a0 * w1;
            acc10 += a1 * w0; acc11 += a1 * w1;
        }
        __syncthreads();
    }
    xs[r0][c0] = acc00; xs[r0][c1] = acc01;
    xs[r1][c0] = acc10; xs[r1][c1] = acc11;
    __syncthreads();
    int bl = tid >> 3, ul = tid & 7;
    int b = b0 + bl;
    int u = (j0 >> 2) + ul;
    float gi = xs[bl][ul * 4 + 0] + bc[j0 + ul * 4 + 0];
    float gf = xs[bl][ul * 4 + 1] + bc[j0 + ul * 4 + 1];
    float gg = xs[bl][ul * 4 + 2] + bc[j0 + ul * 4 + 2];
    float go = xs[bl][ul * 4 + 3] + bc[j0 + ul * 4 + 3];
    float cold = c[b * HDIM + u];
    float c2 = sigmoidf_(gf) * cold + sigmoidf_(gi) * tanhf(gg);
    float h2 = sigmoidf_(go) * tanhf(c2);
    c[b * HDIM + u] = c2;
    hnext[b * HDIM + u] = h2;
}

// Readout + stack update + fused log_softmax (t>=129). One block per batch row.
__global__ __launch_bounds__(256) void outstack_kernel(
        const float* __restrict__ h, const float* __restrict__ Wrf, const float* __restrict__ brf,
        float* __restrict__ V, float* __restrict__ s, float* __restrict__ rt,
        void* __restrict__ dout, const int* __restrict__ flag, int t) {
    int b = blockIdx.x;
    int tid = threadIdx.x;
    int lane = tid & 63, wid = tid >> 6;
    __shared__ float hs[HDIM];
    __shared__ float outs[ROUT];
    __shared__ float wsum[4];
    __shared__ float As[MAXT];
    __shared__ float red[4][SDIM];

    hs[tid] = h[b * HDIM + tid];
    hs[tid + 256] = h[b * HDIM + tid + 256];
    __syncthreads();

    for (int j = wid; j < ROUT; j += 4) {
        const float4* wr4 = (const float4*)(Wrf + (size_t)j * HDIM);
        const float4* h4 = (const float4*)hs;
        float4 wv = wr4[lane];       float4 hv = h4[lane];
        float p = wv.x * hv.x + wv.y * hv.y + wv.z * hv.z + wv.w * hv.w;
        wv = wr4[lane + 64];         hv = h4[lane + 64];
        p += wv.x * hv.x + wv.y * hv.y + wv.z * hv.z + wv.w * hv.w;
        #pragma unroll
        for (int off = 32; off; off >>= 1) p += __shfl_down(p, off, 64);
        if (lane == 0) outs[j] = p + brf[j];
    }
    __syncthreads();

    float uval = sigmoidf_(outs[192]);
    float dval = sigmoidf_(outs[193]);

    if (tid < SDIM) V[((size_t)b * MAXT + t) * SDIM + tid] = outs[tid];

    int i0 = 2 * tid, i1 = i0 + 1;
    float v0 = (i0 < MAXT) ? s[b * MAXT + i0] : 0.f;
    float v1 = (i1 < MAXT) ? s[b * MAXT + i1] : 0.f;
    float pair = v0 + v1;
    float sc = pair;
    #pragma unroll
    for (int off = 1; off < 64; off <<= 1) {
        float y = __shfl_up(sc, off, 64);
        if (lane >= off) sc += y;
    }
    if (lane == 63) wsum[wid] = sc;
    __syncthreads();
    float prefix = 0.f;
    for (int w = 0; w < wid; w++) prefix += wsum[w];
    float total = wsum[0] + wsum[1] + wsum[2] + wsum[3];
    float incl = sc + prefix;
    float excl = incl - pair;
    float P0 = excl + v0;
    float P1 = excl + pair;
    {
        float prod = total - P0;
        float sp = (i0 == t) ? dval : fmaxf(0.f, v0 - fmaxf(0.f, uval - prod));
        float inner = fmaxf(0.f, 1.f - prod - sp);
        float A = fminf(sp, inner);
        if (i0 < MAXT) { s[b * MAXT + i0] = sp; As[i0] = A; }
    }
    {
        float prod = total - P1;
        float sp = (i1 == t) ? dval : fmaxf(0.f, v1 - fmaxf(0.f, uval - prod));
        float inner = fmaxf(0.f, 1.f - prod - sp);
        float A = fminf(sp, inner);
        if (i1 < MAXT) { s[b * MAXT + i1] = sp; As[i1] = A; }
    }
    __syncthreads();

    float racc = 0.f;
    for (int i = wid; i <= t; i += 4)
        racc += As[i] * V[((size_t)b * MAXT + i) * SDIM + lane];
    red[wid][lane] = racc;
    __syncthreads();
    if (tid < SDIM)
        rt[b * SDIM + tid] = red[0][tid] + red[1][tid] + red[2][tid] + red[3][tid];

    // fused log_softmax over outs[64..191] (wave 0; no barriers below; outs stable)
    if (t >= 129 && wid == 0) {
        int isf32 = *flag;
        float a  = outs[64 + lane];
        float bv = outs[128 + lane];
        float m = fmaxf(a, bv);
        #pragma unroll
        for (int off = 32; off; off >>= 1) m = fmaxf(m, __shfl_xor(m, off, 64));
        float e = expf(a - m) + expf(bv - m);
        #pragma unroll
        for (int off = 32; off; off >>= 1) e += __shfl_xor(e, off, 64);
        float ls = logf(e) + m;
        size_t base = ((size_t)(t - 129) * BATCH + b) * IDIM;
        if (isf32) {
            ((float*)dout)[base + lane]      = a - ls;
            ((float*)dout)[base + lane + 64] = bv - ls;
        } else {
            ((bf16*)dout)[base + lane]      = __float2bfloat16(a - ls);
            ((bf16*)dout)[base + lane + 64] = __float2bfloat16(bv - ls);
        }
    }
}

extern "C" void kernel_launch(void* const* d_in, const int* in_sizes, int n_in,
                              void* d_out, int out_size, void* d_ws, size_t ws_size,
                              hipStream_t stream) {
    const void* x   = d_in[0];
    const void* Wih = d_in[1];
    const void* bih = d_in[2];
    const void* Whh = d_in[3];
    const void* bhh = d_in[4];
    const void* Wr  = d_in[5];
    const void* br  = d_in[6];

    int* flag  = (int*)d_ws;
    float* ws  = (float*)d_ws + 16;
    float* Wc  = ws;
    float* bc  = Wc + (size_t)G4 * KTOT;
    float* Wrf = bc + G4;
    float* brf = Wrf + (size_t)ROUT * HDIM;
    float* h0  = brf + 208;
    float* h1  = h0 + BATCH * HDIM;
    float* c   = h1 + BATCH * HDIM;
    float* rt  = c  + BATCH * HDIM;
    float* s   = rt + BATCH * SDIM;
    float* V   = s  + BATCH * MAXT;

    size_t zero_floats = (size_t)(3 * BATCH * HDIM) + BATCH * SDIM
                       + BATCH * MAXT + (size_t)BATCH * MAXT * SDIM;
    hipMemsetAsync(h0, 0, zero_floats * sizeof(float), stream);

    detect_kernel<<<1, 64, 0, stream>>>((const unsigned short*)Wih, flag);
    prep_kernel<<<G4, 256, 0, stream>>>(Wih, bih, Whh, bhh, Wc, bc, flag);
    wr_conv_kernel<<<ROUT, 256, 0, stream>>>(Wr, br, Wrf, brf, flag);

    for (int t = 0; t < MAXT; t++) {
        const float* hp = (t & 1) ? h1 : h0;
        float* hn       = (t & 1) ? h0 : h1;
        int k0 = (t < 129) ? 0 : 128;
        gates_kernel<<<256, 256, 0, stream>>>(x, (size_t)t * BATCH * IDIM,
                                              Wc, bc, hp, rt, hn, c, flag, k0);
        outstack_kernel<<<BATCH, 256, 0, stream>>>(hn, Wrf, brf, V, s, rt, d_out, flag, t);
    }

    (void)in_sizes; (void)n_in; (void)out_size; (void)ws_size;
}

// Round 4
// 13870.277 us; speedup vs baseline: 1.4884x; 1.4884x over previous
//
#include <hip/hip_runtime.h>
#include <hip/hip_bf16.h>
#include <math.h>

#define IDIM 128
#define HDIM 512
#define SDIM 64
#define BATCH 128
#define MAXT 259
#define G4 2048
#define KTOT 704   // 128 (x) + 64 (rt) + 512 (h)
#define ROUT 194   // 64 + 128 + 2
#define KCH 352    // A-chunk (11 MFMA k-steps)
#define APAD 360   // LDS A row stride (elems); 180 words -> 2-way bank alias (free)

typedef __hip_bfloat16 bf16;
typedef __attribute__((ext_vector_type(8))) short short8;
typedef __attribute__((ext_vector_type(4))) float floatx4;

__device__ __forceinline__ float sigmoidf_(float v) { return 1.f / (1.f + expf(-v)); }
__device__ __forceinline__ float b2f(bf16 v) { return __bfloat162float(v); }
__device__ __forceinline__ float load_in(const void* p, size_t i, int isf32) {
    return isf32 ? ((const float*)p)[i] : b2f(((const bf16*)p)[i]);
}
// f32 -> bf16 bits, RNE
__device__ __forceinline__ unsigned short f2bfbits(float v) {
    unsigned u = __builtin_bit_cast(unsigned, v);
    unsigned r = (u + 0x7FFFu + ((u >> 16) & 1u)) >> 16;
    return (unsigned short)r;
}
__device__ __forceinline__ float bfbits2f(unsigned short b) {
    return __builtin_bit_cast(float, (unsigned)b << 16);
}

// Detect input dtype from first 256 uint16s of Wih: f32 data has random low
// halves -> some bf16-exponent >= 0x8F; true bf16 weights (|w|<0.4) never do.
__global__ void detect_kernel(const unsigned short* __restrict__ w, int* __restrict__ flag) {
    if (threadIdx.x == 0) {
        int isf32 = 0;
        for (int i = 0; i < 256; i++) {
            int e = (w[i] >> 7) & 0xFF;
            if (e >= 0x8F) isf32 = 1;
        }
        *flag = isf32;
    }
}

// Build combined gate-interleaved weights in MFMA B-fragment-linear layout:
// row j' = 4u+gate <- source row gate*512+u of [Wih|Whh], split hi/lo bf16.
// Fragment layout: WfH[((jt*22 + ks)*64 + lane)*8 + e] where jt=j'/16,
// ks=k/32, lane=((k%32)/8)*16 + (j'%16), e=k%8 -> a wave's B-frag read is
// 64 consecutive 16B chunks = 1KB coalesced.
__global__ void prep_kernel(const void* __restrict__ Wih, const void* __restrict__ bih,
                            const void* __restrict__ Whh, const void* __restrict__ bhh,
                            unsigned short* __restrict__ WfH, unsigned short* __restrict__ WfL,
                            float* __restrict__ bc, const int* __restrict__ flag) {
    int isf32 = *flag;
    int jp = blockIdx.x;              // 0..2047
    int u = jp >> 2, gate = jp & 3;
    int src = gate * HDIM + u;
    int jt = jp >> 4, jn = jp & 15;
    for (int k = threadIdx.x; k < KTOT; k += blockDim.x) {
        float v = (k < 192) ? load_in(Wih, (size_t)src * 192 + k, isf32)
                            : load_in(Whh, (size_t)src * HDIM + (k - 192), isf32);
        unsigned short hi = f2bfbits(v);
        unsigned short lo = f2bfbits(v - bfbits2f(hi));   // ==0 if v already bf16
        int ks = k >> 5, q = (k & 31) >> 3, e = k & 7;
        size_t d = (((size_t)jt * 22 + ks) * 64 + (q * 16 + jn)) * 8 + e;
        WfH[d] = hi;
        WfL[d] = lo;
    }
    if (threadIdx.x == 0)
        bc[jp] = load_in(bih, src, isf32) + load_in(bhh, src, isf32);
}

__global__ void wr_conv_kernel(const void* __restrict__ Wr, const void* __restrict__ br,
                               float* __restrict__ Wrf, float* __restrict__ brf,
                               const int* __restrict__ flag) {
    int isf32 = *flag;
    int j = blockIdx.x;
    for (int k = threadIdx.x; k < HDIM; k += blockDim.x)
        Wrf[(size_t)j * HDIM + k] = load_in(Wr, (size_t)j * HDIM + k, isf32);
    if (threadIdx.x == 0) brf[j] = load_in(br, j, isf32);
}

// Gates GEMM (128x2048, K=704) via bf16 MFMA with A hi/lo split + fused LSTM cell.
// Block = 32 b-rows x 32 j'-cols; 4 waves each own a 16x16 quadrant.
// A (x|rt|h) staged hi/lo in LDS per 352-chunk; W streamed from global (L2-resident,
// fragment-linear -> 1KB coalesced loads). Grid = 4*64 = 256 blocks.
__global__ __launch_bounds__(256) void gates_kernel(
        const void* __restrict__ x, size_t xoff, int use_x,
        const unsigned short* __restrict__ WfH, const unsigned short* __restrict__ WfL,
        const float* __restrict__ bc,
        const float* __restrict__ hprev, const float* __restrict__ rt,
        float* __restrict__ hnext, float* __restrict__ cst,
        const int* __restrict__ flag) {
    __shared__ unsigned short Ah[32][APAD];
    __shared__ unsigned short Al[32][APAD];
    __shared__ float gtile[32][36];
    int isf32 = *flag;
    int tid = threadIdx.x;
    int lane = tid & 63, wave = tid >> 6;
    int bm = blockIdx.x & 3, bn = blockIdx.x >> 2;
    int b0 = bm * 32, j0 = bn * 32;
    int mrow = (wave & 1) * 16, nq = wave >> 1, ncol = nq * 16;
    int jt = bn * 2 + nq;
    const unsigned short* wbaseH = WfH + ((size_t)jt * 22 * 64 * 8) + (size_t)lane * 8;
    const unsigned short* wbaseL = WfL + ((size_t)jt * 22 * 64 * 8) + (size_t)lane * 8;

    floatx4 acc = {0.f, 0.f, 0.f, 0.f};
    int arow = mrow + (lane & 15);
    int acol0 = (lane >> 4) * 8;

    for (int ch = 0; ch < 2; ch++) {
        int kc = ch * KCH;
        // stage A chunk [kc, kc+352): 1408 groups of 8 elems
        for (int e = tid; e < 32 * 44; e += 256) {
            int r = e / 44, g = e - r * 44;
            int k = kc + g * 8;
            int b = b0 + r;
            short8 hi, lo;
            if (k < 128) {
                if (use_x) {
                    if (isf32) {
                        const float* xf = (const float*)x + xoff + (size_t)b * IDIM + k;
                        #pragma unroll
                        for (int i = 0; i < 8; i++) {
                            unsigned short hb = f2bfbits(xf[i]);
                            hi[i] = (short)hb;
                            lo[i] = (short)f2bfbits(xf[i] - bfbits2f(hb));
                        }
                    } else {
                        hi = *(const short8*)((const unsigned short*)x + xoff + (size_t)b * IDIM + k);
                        #pragma unroll
                        for (int i = 0; i < 8; i++) lo[i] = 0;
                    }
                } else {
                    #pragma unroll
                    for (int i = 0; i < 8; i++) { hi[i] = 0; lo[i] = 0; }
                }
            } else {
                const float* src = (k < 192) ? (rt + (size_t)b * SDIM + (k - 128))
                                             : (hprev + (size_t)b * HDIM + (k - 192));
                #pragma unroll
                for (int i = 0; i < 8; i++) {
                    float v = src[i];
                    unsigned short hb = f2bfbits(v);
                    hi[i] = (short)hb;
                    lo[i] = (short)f2bfbits(v - bfbits2f(hb));
                }
            }
            *(short8*)&Ah[r][g * 8] = hi;
            *(short8*)&Al[r][g * 8] = lo;
        }
        __syncthreads();
        int ks0 = ch * 11;
        #pragma unroll
        for (int ks = 0; ks < 11; ks++) {
            int kk = ks * 32;
            short8 a_hi = *(const short8*)&Ah[arow][kk + acol0];
            short8 a_lo = *(const short8*)&Al[arow][kk + acol0];
            short8 b_hi = *(const short8*)(wbaseH + (size_t)(ks0 + ks) * 64 * 8);
            acc = __builtin_amdgcn_mfma_f32_16x16x32_bf16(a_hi, b_hi, acc, 0, 0, 0);
            acc = __builtin_amdgcn_mfma_f32_16x16x32_bf16(a_lo, b_hi, acc, 0, 0, 0);
            if (isf32) {
                short8 b_lo = *(const short8*)(wbaseL + (size_t)(ks0 + ks) * 64 * 8);
                acc = __builtin_amdgcn_mfma_f32_16x16x32_bf16(a_hi, b_lo, acc, 0, 0, 0);
            }
        }
        __syncthreads();
    }
    // C/D layout: m = mrow + (lane>>4)*4 + reg, n = ncol + (lane&15)
    #pragma unroll
    for (int r2 = 0; r2 < 4; r2++)
        gtile[mrow + (lane >> 4) * 4 + r2][ncol + (lane & 15)] = acc[r2];
    __syncthreads();
    // cell epilogue: 32 b x 8 u per block, 4 consecutive j' = gates of one u
    int bl = tid >> 3, ul = tid & 7;
    int b = b0 + bl, u = (j0 >> 2) + ul;
    float4 g4 = *(const float4*)&gtile[bl][ul * 4];
    float gi = g4.x + bc[j0 + ul * 4 + 0];
    float gf = g4.y + bc[j0 + ul * 4 + 1];
    float gg = g4.z + bc[j0 + ul * 4 + 2];
    float go = g4.w + bc[j0 + ul * 4 + 3];
    float cold = cst[b * HDIM + u];
    float c2 = sigmoidf_(gf) * cold + sigmoidf_(gi) * tanhf(gg);
    float h2 = sigmoidf_(go) * tanhf(c2);
    cst[b * HDIM + u] = c2;
    hnext[b * HDIM + u] = h2;
}

// Readout + stack update + fused log_softmax (t>=129). One block per batch row.
__global__ __launch_bounds__(256) void outstack_kernel(
        const float* __restrict__ h, const float* __restrict__ Wrf, const float* __restrict__ brf,
        float* __restrict__ V, float* __restrict__ s, float* __restrict__ rt,
        void* __restrict__ dout, const int* __restrict__ flag, int t) {
    int b = blockIdx.x;
    int tid = threadIdx.x;
    int lane = tid & 63, wid = tid >> 6;
    __shared__ float hs[HDIM];
    __shared__ float outs[ROUT];
    __shared__ float wsum[4];
    __shared__ float As[MAXT];
    __shared__ float red[4][SDIM];

    hs[tid] = h[b * HDIM + tid];
    hs[tid + 256] = h[b * HDIM + tid + 256];
    __syncthreads();

    for (int j = wid; j < ROUT; j += 4) {
        const float4* wr4 = (const float4*)(Wrf + (size_t)j * HDIM);
        const float4* h4 = (const float4*)hs;
        float4 wv = wr4[lane];       float4 hv = h4[lane];
        float p = wv.x * hv.x + wv.y * hv.y + wv.z * hv.z + wv.w * hv.w;
        wv = wr4[lane + 64];         hv = h4[lane + 64];
        p += wv.x * hv.x + wv.y * hv.y + wv.z * hv.z + wv.w * hv.w;
        #pragma unroll
        for (int off = 32; off; off >>= 1) p += __shfl_down(p, off, 64);
        if (lane == 0) outs[j] = p + brf[j];
    }
    __syncthreads();

    float uval = sigmoidf_(outs[192]);
    float dval = sigmoidf_(outs[193]);

    if (tid < SDIM) V[((size_t)b * MAXT + t) * SDIM + tid] = outs[tid];

    int i0 = 2 * tid, i1 = i0 + 1;
    float v0 = (i0 < MAXT) ? s[b * MAXT + i0] : 0.f;
    float v1 = (i1 < MAXT) ? s[b * MAXT + i1] : 0.f;
    float pair = v0 + v1;
    float sc = pair;
    #pragma unroll
    for (int off = 1; off < 64; off <<= 1) {
        float y = __shfl_up(sc, off, 64);
        if (lane >= off) sc += y;
    }
    if (lane == 63) wsum[wid] = sc;
    __syncthreads();
    float prefix = 0.f;
    for (int w = 0; w < wid; w++) prefix += wsum[w];
    float total = wsum[0] + wsum[1] + wsum[2] + wsum[3];
    float incl = sc + prefix;
    float excl = incl - pair;
    float P0 = excl + v0;
    float P1 = excl + pair;
    {
        float prod = total - P0;
        float sp = (i0 == t) ? dval : fmaxf(0.f, v0 - fmaxf(0.f, uval - prod));
        float inner = fmaxf(0.f, 1.f - prod - sp);
        float A = fminf(sp, inner);
        if (i0 < MAXT) { s[b * MAXT + i0] = sp; As[i0] = A; }
    }
    {
        float prod = total - P1;
        float sp = (i1 == t) ? dval : fmaxf(0.f, v1 - fmaxf(0.f, uval - prod));
        float inner = fmaxf(0.f, 1.f - prod - sp);
        float A = fminf(sp, inner);
        if (i1 < MAXT) { s[b * MAXT + i1] = sp; As[i1] = A; }
    }
    __syncthreads();

    float racc = 0.f;
    for (int i = wid; i <= t; i += 4)
        racc += As[i] * V[((size_t)b * MAXT + i) * SDIM + lane];
    red[wid][lane] = racc;
    __syncthreads();
    if (tid < SDIM)
        rt[b * SDIM + tid] = red[0][tid] + red[1][tid] + red[2][tid] + red[3][tid];

    if (t >= 129 && wid == 0) {
        int isf32 = *flag;
        float a  = outs[64 + lane];
        float bv = outs[128 + lane];
        float m = fmaxf(a, bv);
        #pragma unroll
        for (int off = 32; off; off >>= 1) m = fmaxf(m, __shfl_xor(m, off, 64));
        float e = expf(a - m) + expf(bv - m);
        #pragma unroll
        for (int off = 32; off; off >>= 1) e += __shfl_xor(e, off, 64);
        float ls = logf(e) + m;
        size_t base = ((size_t)(t - 129) * BATCH + b) * IDIM;
        if (isf32) {
            ((float*)dout)[base + lane]      = a - ls;
            ((float*)dout)[base + lane + 64] = bv - ls;
        } else {
            ((bf16*)dout)[base + lane]      = __float2bfloat16(a - ls);
            ((bf16*)dout)[base + lane + 64] = __float2bfloat16(bv - ls);
        }
    }
}

extern "C" void kernel_launch(void* const* d_in, const int* in_sizes, int n_in,
                              void* d_out, int out_size, void* d_ws, size_t ws_size,
                              hipStream_t stream) {
    const void* x   = d_in[0];
    const void* Wih = d_in[1];
    const void* bih = d_in[2];
    const void* Whh = d_in[3];
    const void* bhh = d_in[4];
    const void* Wr  = d_in[5];
    const void* br  = d_in[6];

    char* base = (char*)d_ws;
    int* flag = (int*)base;
    unsigned short* WfH = (unsigned short*)(base + 64);
    unsigned short* WfL = WfH + (size_t)G4 * KTOT;
    float* bc  = (float*)(base + 64 + 2 * (size_t)G4 * KTOT * sizeof(unsigned short));
    float* Wrf = bc + G4;
    float* brf = Wrf + (size_t)ROUT * HDIM;
    float* h0  = brf + 208;
    float* h1  = h0 + BATCH * HDIM;
    float* c   = h1 + BATCH * HDIM;
    float* rt  = c  + BATCH * HDIM;
    float* s   = rt + BATCH * SDIM;
    float* V   = s  + BATCH * MAXT;

    size_t zero_floats = (size_t)(3 * BATCH * HDIM) + BATCH * SDIM
                       + BATCH * MAXT + (size_t)BATCH * MAXT * SDIM;
    hipMemsetAsync(h0, 0, zero_floats * sizeof(float), stream);

    detect_kernel<<<1, 64, 0, stream>>>((const unsigned short*)Wih, flag);
    prep_kernel<<<G4, 256, 0, stream>>>(Wih, bih, Whh, bhh, WfH, WfL, bc, flag);
    wr_conv_kernel<<<ROUT, 256, 0, stream>>>(Wr, br, Wrf, brf, flag);

    for (int t = 0; t < MAXT; t++) {
        const float* hp = (t & 1) ? h1 : h0;
        float* hn       = (t & 1) ? h0 : h1;
        int use_x = (t < 129) ? 1 : 0;
        gates_kernel<<<256, 256, 0, stream>>>(x, (size_t)t * BATCH * IDIM, use_x,
                                              WfH, WfL, bc, hp, rt, hn, c, flag);
        outstack_kernel<<<BATCH, 256, 0, stream>>>(hn, Wrf, brf, V, s, rt, d_out, flag, t);
    }

    (void)in_sizes; (void)n_in; (void)out_size; (void)ws_size;
}